// Round 15
// baseline (157.442 us; speedup 1.0000x reference)
//
#include <hip/hip_runtime.h>

// Bilinear backward warp: img [B,C,H,W] f32, flo [B,2,H,W] f32 -> out [B,C,H,W] f32
// B=8, C=64, H=256, W=448
//
// R15: fewer, fatter barrier layers. Empirical cross-round law:
// wall ~= layers/CU x (1.7us fixed + work). R3: 64x2.0, R7: 32x3.4 (=109.7).
// Here: 4 channels per round, NO double buffer, 2-barrier mega-round:
//   stage 4 bands (72KB, same footprint/residency as R7) -> barrier ->
//   compute+store 4 channels -> barrier -> restage.
// Layers/CU drop 32 -> 16; exposed stage latency (~0.3-0.5us/round) is the
// price. R=4 keeps VGPR ~64 (R14's R=8 blew to 128 and lost residency).

#define BN 8
#define CN 64
#define HN 256
#define WN 448
#define HW (HN * WN)
#define R 4              // output rows per block
#define BAND 10          // staged img rows per channel (lo = h0-3)
#define TPB WN           // 448 threads = 7 waves
#define NXCD 8
#define CSPLIT 2
#define CLOOP (CN / CSPLIT)   // 32 channels per block
#define CHPER 4
#define ROUNDS (CLOOP / CHPER)   // 8 mega-rounds

typedef __attribute__((address_space(1))) const void glb_v;
typedef __attribute__((address_space(3))) void lds_v;

__global__ __launch_bounds__(TPB) void warp_kernel(const float* __restrict__ img,
                                                   const float* __restrict__ flo,
                                                   float* __restrict__ out) {
    // 4 bands x (4480+4) floats = 71744 B -> 2 blocks/CU (same as R7)
    __shared__ float lds[4][BAND * WN + 4];

    // XCD swizzle: 1024 blocks = 128/XCD = one batch per XCD.
    const int nwg = gridDim.x;            // 1024
    const int cpx = nwg / NXCD;           // 128
    const int bid = blockIdx.x;
    const int wgid = (bid % NXCD) * cpx + (bid / NXCD);

    const int b    = wgid / cpx;          // 0..7
    const int rem  = wgid % cpx;          // 0..127
    const int tile = rem >> 1;            // 0..63
    const int ch0  = (rem & 1) * CLOOP;   // 0 or 32
    const int h0   = tile * R;
    const int w    = threadIdx.x;         // 0..447

    int lo = h0 - 3;
    lo = lo < 0 ? 0 : (lo > HN - BAND ? HN - BAND : lo);

    const float* imgb = img + (size_t)b * CN * HW;
    const float* flob = flo + (size_t)b * 2 * HW;

    // ---- per-pixel setup, channel-invariant ----
    float wa[R], wb[R], wc[R], wd[R];
    int sA[R], sB[R];       // band-relative LDS word offsets
    int gA[R], gB[R];       // plane-relative global word offsets (fallback)
    int dx_[R];
    bool fb[R];
    bool anyfb = false;
#pragma unroll
    for (int r = 0; r < R; ++r) {
        const int h = h0 + r;
        const int hw = h * WN + w;
        const float fx = flob[hw];
        const float fy = flob[HW + hw];
        const float x = (float)w + fx;
        const float y = (float)h + fy;
        int x0 = (int)x;                 // trunc toward zero (matches ref)
        int x1 = x0 + 1;
        int y0 = (int)y;
        int y1 = y0 + 1;
        x0 = min(max(x0, 0), WN - 1);
        x1 = min(max(x1, 0), WN - 1);
        y0 = min(max(y0, 0), HN - 1);
        y1 = min(max(y1, 0), HN - 1);
        const float x0f = (float)x0, x1f = (float)x1;
        const float y0f = (float)y0, y1f = (float)y1;
        wa[r] = (x1f - x) * (y1f - y);
        wb[r] = (x1f - x) * (y - y0f);
        wc[r] = (x - x0f) * (y1f - y);
        wd[r] = (x - x0f) * (y - y0f);
        dx_[r] = x1 - x0;                // 0 only at l/r edge clip
        const bool inband = (y0 >= lo) && (y1 <= lo + BAND - 1);
        fb[r] = !inband;
        anyfb |= fb[r];
        const int rA = min(max(y0 - lo, 0), BAND - 1);
        const int rB = min(max(y1 - lo, 0), BAND - 1);
        sA[r] = rA * WN + x0;
        sB[r] = rB * WN + x0;
        gA[r] = y0 * WN + x0;
        gB[r] = y1 * WN + x0;
    }
    const bool dirty = __any(anyfb);    // wave-uniform, rare

    const int wave = threadIdx.x >> 6;   // 0..6
    const int lane = threadIdx.x & 63;

    // ---- staging: 4 channels x (17 x 1KB + 2 x 256B) distributed over 7 waves ----
    auto stage4 = [&](int cq0) {         // cq0 = first global channel of quad
        // 68 width-16 chunks: id = q*17 + s
        for (int id = wave; id < 68; id += 7) {
            const int q = id / 17;
            const int s = id - q * 17;
            const float* src = imgb + (size_t)(cq0 + q) * HW + (size_t)lo * WN;
            __builtin_amdgcn_global_load_lds(
                (glb_v*)(src + s * 256 + lane * 4),
                (lds_v*)(&lds[q][0] + s * 256), 16, 0, 0);
        }
        // 8 width-4 tails: t = q*2 + j
        for (int t = wave; t < 8; t += 7) {
            const int q = t >> 1;
            const int j = t & 1;
            const float* src = imgb + (size_t)(cq0 + q) * HW + (size_t)lo * WN;
            const int base = 17 * 256 + j * 64;
            __builtin_amdgcn_global_load_lds(
                (glb_v*)(src + base + lane),
                (lds_v*)(&lds[q][0] + base), 4, 0, 0);
        }
    };

    float* outp = out + (size_t)b * CN * HW + (size_t)ch0 * HW + (size_t)h0 * WN + w;

    for (int k = 0; k < ROUNDS; ++k) {
        const int m = CHPER * k;              // local channel base of this round
        stage4(ch0 + m);
        __syncthreads();                      // stage landed (exposed latency)

        if (!dirty) {
#pragma unroll
            for (int q = 0; q < CHPER; ++q) {
                const float* buf = &lds[q][0];
#pragma unroll
                for (int r = 0; r < R; ++r) {
                    const float a0 = buf[sA[r]];
                    const float a1 = buf[sA[r] + 1];   // ds_read2_b32 pair
                    const float b0 = buf[sB[r]];
                    const float b1 = buf[sB[r] + 1];
                    const float Ic = dx_[r] ? a1 : a0;
                    const float Id = dx_[r] ? b1 : b0;
                    outp[(size_t)(m + q) * HW + r * WN] =
                        wa[r] * a0 + wb[r] * b0 + wc[r] * Ic + wd[r] * Id;
                }
            }
        } else {
#pragma unroll
            for (int q = 0; q < CHPER; ++q) {
                const float* buf = &lds[q][0];
                const float* pg = imgb + (size_t)(ch0 + m + q) * HW;
#pragma unroll
                for (int r = 0; r < R; ++r) {
                    float a0 = buf[sA[r]];
                    float a1 = buf[sA[r] + 1];
                    float b0 = buf[sB[r]];
                    float b1 = buf[sB[r] + 1];
                    if (fb[r]) {
                        a0 = pg[gA[r]];
                        a1 = pg[gA[r] + dx_[r]];
                        b0 = pg[gB[r]];
                        b1 = pg[gB[r] + dx_[r]];
                    }
                    const float Ic = dx_[r] ? a1 : a0;
                    const float Id = dx_[r] ? b1 : b0;
                    outp[(size_t)(m + q) * HW + r * WN] =
                        wa[r] * a0 + wb[r] * b0 + wc[r] * Ic + wd[r] * Id;
                }
            }
        }
        __syncthreads();                      // all reads done before restage
    }
}

extern "C" void kernel_launch(void* const* d_in, const int* in_sizes, int n_in,
                              void* d_out, int out_size, void* d_ws, size_t ws_size,
                              hipStream_t stream) {
    const float* img = (const float*)d_in[0];
    const float* flo = (const float*)d_in[1];
    float* out = (float*)d_out;

    const int grid = BN * (HN / R) * CSPLIT;   // 1024 blocks
    warp_kernel<<<grid, TPB, 0, stream>>>(img, flo, out);
}